// Round 1
// baseline (447.260 us; speedup 1.0000x reference)
//
#include <hip/hip_runtime.h>
#include <math.h>

#define MAXP 8732
#define MAXG 64
#define NBINS 8192   // float_bits >> 18 (covers all non-negative floats incl. inf)

// IoU with the exact op order of the numpy reference; contraction off so the
// decision-critical values (argmax ties, <0.5 threshold) match numpy bit-for-bit.
__device__ __forceinline__ float iou_one(float px1,float py1,float px2,float py2,float area_p,
                                         float gx1,float gy1,float gx2,float gy2,float area_g){
#pragma clang fp contract(off)
  float ix = fminf(px2,gx2) - fmaxf(px1,gx1); ix = fmaxf(ix,0.0f);
  float iy = fminf(py2,gy2) - fmaxf(py1,gy1); iy = fmaxf(iy,0.0f);
  float inter = ix*iy;
  return inter / (area_p + area_g - inter);
}

// K1a: for each (b,g), best_priory_idx = first argmax over priors.
// One wave scans all P priors for one g; packed (iou_bits<<32 | P-1-p) max.
__global__ __launch_bounds__(256) void k_bestprior(
    const float* __restrict__ priors, const float* __restrict__ truth,
    int* __restrict__ bestp, int B, int P, int G)
{
#pragma clang fp contract(off)
  const int SUB = 8;
  int b = blockIdx.x / SUB, sub = blockIdx.x % SUB;
  int lane = threadIdx.x & 63, wv = threadIdx.x >> 6;
  int slot = sub*4 + wv;              // 0..31 wave slots per batch
  for (int g = slot; g < G; g += SUB*4) {
    const float* t = truth + ((long)b*G + g)*5;
    float gx1=t[0], gy1=t[1], gx2=t[2], gy2=t[3];
    float ag = (gx2-gx1)*(gy2-gy1);
    unsigned long long best = 0ull;
    for (int p = lane; p < P; p += 64) {
      float4 pr = ((const float4*)priors)[p];
      float px1 = pr.x - 0.5f*pr.z, py1 = pr.y - 0.5f*pr.w;
      float px2 = pr.x + 0.5f*pr.z, py2 = pr.y + 0.5f*pr.w;
      float ap = (px2-px1)*(py2-py1);
      float v = iou_one(px1,py1,px2,py2,ap, gx1,gy1,gx2,gy2,ag);
      unsigned long long key = ((unsigned long long)__float_as_uint(v)<<32) | (unsigned)(P-1-p);
      if (key > best) best = key;
    }
    for (int o=32;o;o>>=1){
      unsigned lo = __shfl_xor((unsigned)best, o);
      unsigned hi = __shfl_xor((unsigned)(best>>32), o);
      unsigned long long other = ((unsigned long long)hi<<32)|lo;
      if (other > best) best = other;
    }
    if (lane==0) bestp[(long)b*G + g] = P - 1 - (int)(unsigned)(best & 0xffffffffu);
  }
}

// K1b: per-prior best gt (first-max), forced overrides (last g wins),
// conf_t, and fused smooth-L1 (positives only). Partial sums -> atomics.
__global__ __launch_bounds__(256) void k_match(
    const float* __restrict__ pred_loc, const float* __restrict__ priors,
    const float* __restrict__ truth, const int* __restrict__ bestp,
    int* __restrict__ conf_t, int* __restrict__ num_pos, float* __restrict__ accum,
    int B, int P, int G)
{
#pragma clang fp contract(off)
  const int SUB = 8;
  int b = blockIdx.x / SUB, sub = blockIdx.x % SUB;
  int tid = threadIdx.x;
  __shared__ float s_tb[MAXG*5];
  __shared__ float s_ag[MAXG];
  __shared__ int   s_bp[MAXG];
  __shared__ float s_rf[4];
  __shared__ int   s_ri[4];
  for (int i = tid; i < G*5; i += 256) s_tb[i] = truth[(long)b*G*5 + i];
  if (tid < G) s_bp[tid] = bestp[(long)b*G + tid];
  __syncthreads();
  if (tid < G) {
    float x1=s_tb[tid*5], y1=s_tb[tid*5+1], x2=s_tb[tid*5+2], y2=s_tb[tid*5+3];
    s_ag[tid] = (x2-x1)*(y2-y1);
  }
  __syncthreads();
  int chunk = (P + SUB - 1)/SUB;
  int p0 = sub*chunk, p1 = min(p0+chunk, P);
  float lacc = 0.f; int pcnt = 0;
  for (int p = p0 + tid; p < p1; p += 256) {
    float4 pr = ((const float4*)priors)[p];
    float px1 = pr.x - 0.5f*pr.z, py1 = pr.y - 0.5f*pr.w;
    float px2 = pr.x + 0.5f*pr.z, py2 = pr.y + 0.5f*pr.w;
    float ap = (px2-px1)*(py2-py1);
    float bv = -1.0f; int bg = 0;
    for (int g = 0; g < G; ++g) {
      float v = iou_one(px1,py1,px2,py2,ap,
                        s_tb[g*5],s_tb[g*5+1],s_tb[g*5+2],s_tb[g*5+3], s_ag[g]);
      if (v > bv) { bv = v; bg = g; }       // first-max = np.argmax semantics
    }
    float ov = bv; int gi = bg;
    for (int g = 0; g < G; ++g) if (s_bp[g] == p) { ov = 2.0f; gi = g; }  // last wins
    float lb = s_tb[gi*5+4];
    int conf = (ov < 0.5f) ? 0 : (int)(lb + 1.0f);
    conf_t[(long)b*P + p] = conf;
    if (conf > 0) {
      pcnt++;
      float mx1=s_tb[gi*5], my1=s_tb[gi*5+1], mx2=s_tb[gi*5+2], my2=s_tb[gi*5+3];
      float l0 = ((mx1+mx2)*0.5f - pr.x)/pr.z;
      float l1 = ((my1+my2)*0.5f - pr.y)/pr.w;
      float l2 = logf((mx2-mx1)/pr.z);
      float l3 = logf((my2-my1)/pr.w);
      float4 pv = *((const float4*)(pred_loc + ((long)b*P + p)*4));
      float d, s = 0.f;
      d = fabsf(pv.x - l0); s += d < 1.f ? 0.5f*d*d : d - 0.5f;
      d = fabsf(pv.y - l1); s += d < 1.f ? 0.5f*d*d : d - 0.5f;
      d = fabsf(pv.z - l2); s += d < 1.f ? 0.5f*d*d : d - 0.5f;
      d = fabsf(pv.w - l3); s += d < 1.f ? 0.5f*d*d : d - 0.5f;
      lacc += s;
    }
  }
  int lane = tid & 63, wv = tid >> 6;
  for (int o=32;o;o>>=1){ lacc += __shfl_xor(lacc,o); pcnt += __shfl_xor(pcnt,o); }
  if (lane==0){ s_rf[wv]=lacc; s_ri[wv]=pcnt; }
  __syncthreads();
  if (tid==0){
    atomicAdd(&accum[0], s_rf[0]+s_rf[1]+s_rf[2]+s_rf[3]);
    atomicAdd(&num_pos[b], s_ri[0]+s_ri[1]+s_ri[2]+s_ri[3]);
  }
}

// K2: one wave per (b,p) row: lse = max + log(sum exp(x-max)), ce = lse - x[conf_t].
// Also accumulates sum(ce * pos).
__global__ __launch_bounds__(256) void k_ce(
  const float* __restrict__ pred_conf, const int* __restrict__ conf_t,
  float* __restrict__ ce, float* __restrict__ accum, long rows, int C)
{
  const int lane = threadIdx.x & 63;
  const int wv = threadIdx.x >> 6;
  long wave = (long)blockIdx.x * 4 + wv;
  long nw = (long)gridDim.x * 4;
  float pacc = 0.f;
  for (long row = wave; row < rows; row += nw) {
    const float* cp = pred_conf + row * (long)C;
    float x0 = (lane      < C) ? cp[lane]      : -INFINITY;
    float x1 = (64 + lane < C) ? cp[64 + lane] : -INFINITY;
    float m = fmaxf(x0, x1);
    for (int o = 32; o; o >>= 1) m = fmaxf(m, __shfl_xor(m, o));
    float s = expf(x0 - m) + expf(x1 - m);   // exp(-inf)=0 handles masked lanes
    for (int o = 32; o; o >>= 1) s += __shfl_xor(s, o);
    float lse = logf(s) + m;
    int ct = conf_t[row];
    float tA = __shfl(x0, ct & 63);
    float tB = __shfl(x1, (ct - 64) & 63);
    float cev = lse - (ct < 64 ? tA : tB);
    if (lane == 0) { ce[row] = cev; if (ct > 0) pacc += cev; }
  }
  __shared__ float s_f[4];
  if (lane == 0) s_f[wv] = pacc;
  __syncthreads();
  if (threadIdx.x == 0) atomicAdd(&accum[1], s_f[0]+s_f[1]+s_f[2]+s_f[3]);
}

// K3: the quirky negative mask. neg[p] = perm[p] < num_neg (perm = stable asc argsort
// of loss_mine). Equivalent: for j<num_neg, add ce[r_j]*(1-pos[r_j]) where r_j = stable
// rank of loss_mine[j]. Rank via 8192-bin counting-sort (float bits order-preserving).
__global__ __launch_bounds__(1024) void k_negsel(
    const float* __restrict__ ce, const int* __restrict__ conf_t,
    const int* __restrict__ num_pos, float* __restrict__ accum, int P)
{
  const int b = blockIdx.x;
  const int tid = threadIdx.x;
  const int lane = tid & 63, wv = tid >> 6;
  __shared__ unsigned s_bits[MAXP];
  __shared__ unsigned s_hist[NBINS];
  __shared__ unsigned short s_grp[MAXP];
  __shared__ unsigned s_wsum[16];
  __shared__ float s_facc[16];

  long base = (long)b * P;
  for (int p = tid; p < P; p += 1024) {
    int ct = conf_t[base + p];
    float v = ce[base + p];
    s_bits[p] = (ct > 0) ? 0u : __float_as_uint(v);   // loss_mine bits (>=0, monotone)
  }
  for (int i = tid; i < NBINS; i += 1024) s_hist[i] = 0;
  __syncthreads();
  for (int p = tid; p < P; p += 1024) atomicAdd(&s_hist[s_bits[p] >> 18], 1u);
  __syncthreads();
  // exclusive scan over NBINS, 8 bins/thread
  unsigned loc[8]; unsigned tot = 0;
  int hbase = tid * 8;
#pragma unroll
  for (int i = 0; i < 8; ++i) { loc[i] = s_hist[hbase + i]; tot += loc[i]; }
  unsigned incl = tot;
  for (int o = 1; o < 64; o <<= 1) {
    unsigned n = __shfl_up(incl, o);
    if (lane >= o) incl += n;
  }
  if (lane == 63) s_wsum[wv] = incl;
  __syncthreads();
  if (tid == 0) {
    unsigned r = 0;
    for (int i = 0; i < 16; ++i) { unsigned t = s_wsum[i]; s_wsum[i] = r; r += t; }
  }
  __syncthreads();
  unsigned run = incl - tot + s_wsum[wv];
#pragma unroll
  for (int i = 0; i < 8; ++i) { s_hist[hbase + i] = run; run += loc[i]; }
  __syncthreads();
  // scatter into bucket-grouped order (order within bucket irrelevant: stable
  // tie-break done by (bits, index) compare below)
  for (int p = tid; p < P; p += 1024) {
    unsigned slot = atomicAdd(&s_hist[s_bits[p] >> 18], 1u);
    s_grp[slot] = (unsigned short)p;
  }
  __syncthreads();
  int npos = num_pos[b];
  int nneg = min(3 * npos, P - 1);
  float acc = 0.f;
  for (int j = tid; j < nneg; j += 1024) {
    unsigned bj = s_bits[j];
    unsigned bu = bj >> 18;
    unsigned start = bu ? s_hist[bu - 1] : 0u;   // after scatter: hist[b] = end of b
    unsigned end = s_hist[bu];
    unsigned cnt = 0;
    for (unsigned t = start; t < end; ++t) {
      int k = s_grp[t];
      unsigned bk = s_bits[k];
      cnt += (bk < bj) || (bk == bj && k < j);
    }
    unsigned rk = start + cnt;                   // stable ascending rank of j
    if (conf_t[base + rk] == 0) acc += ce[base + rk];
  }
  for (int o=32;o;o>>=1) acc += __shfl_xor(acc,o);
  if (lane==0) s_facc[wv]=acc;
  __syncthreads();
  if (tid==0){ float f=0; for(int i=0;i<16;i++) f+=s_facc[i]; atomicAdd(&accum[2], f); }
}

__global__ void k_final(const int* __restrict__ num_pos, const float* __restrict__ accum,
                        float* __restrict__ out, int B)
{
  int s = 0;
  for (int i = threadIdx.x; i < B; i += 64) s += num_pos[i];
  for (int o=32;o;o>>=1) s += __shfl_xor(s,o);
  if (threadIdx.x == 0) {
    float N = (float)s;
    out[0] = accum[0] / N;
    out[1] = (accum[1] + accum[2]) / N;
  }
}

extern "C" void kernel_launch(void* const* d_in, const int* in_sizes, int n_in,
                              void* d_out, int out_size, void* d_ws, size_t ws_size,
                              hipStream_t stream)
{
  const float* pred_conf = (const float*)d_in[0];
  const float* pred_loc  = (const float*)d_in[1];
  const float* priors    = (const float*)d_in[2];
  const float* truth     = (const float*)d_in[3];
  int  P  = in_sizes[2] / 4;
  long BP = in_sizes[1] / 4;          // B*P
  int  B  = (int)(BP / P);
  int  C  = (int)(in_sizes[0] / BP);
  int  G  = in_sizes[3] / (B * 5);

  char* ws = (char*)d_ws;
  size_t off = 0;
  int*   conf_t  = (int*)(ws + off);   off += sizeof(int)   * (size_t)BP;
  float* ce      = (float*)(ws + off); off += sizeof(float) * (size_t)BP;
  int*   bestp   = (int*)(ws + off);   off += sizeof(int)   * (size_t)B * G;
  int*   num_pos = (int*)(ws + off);   off += sizeof(int)   * (size_t)B;
  float* accum   = (float*)(ws + off); off += 4 * sizeof(float);

  // zero num_pos + accum (contiguous) every launch
  hipMemsetAsync(num_pos, 0, sizeof(int) * (size_t)B + 4 * sizeof(float), stream);

  k_bestprior<<<B * 8, 256, 0, stream>>>(priors, truth, bestp, B, P, G);
  k_match    <<<B * 8, 256, 0, stream>>>(pred_loc, priors, truth, bestp,
                                         conf_t, num_pos, accum, B, P, G);
  k_ce       <<<2048, 256, 0, stream>>>(pred_conf, conf_t, ce, accum, BP, C);
  k_negsel   <<<B, 1024, 0, stream>>>(ce, conf_t, num_pos, accum, P);
  k_final    <<<1, 64, 0, stream>>>(num_pos, accum, (float*)d_out, B);
}

// Round 2
// 292.462 us; speedup vs baseline: 1.5293x; 1.5293x over previous
//
#include <hip/hip_runtime.h>
#include <math.h>

#define MAXP 8732
#define MAXG 64
#define NBINS 16384   // float_bits >> 17 (sign+exp+6 mantissa bits)
#define NZW   ((MAXP + 63) / 64)

// IoU with the exact op order of the numpy reference; contraction off so the
// decision-critical values (argmax ties, <0.5 threshold) match numpy bit-for-bit.
__device__ __forceinline__ float iou_one(float px1,float py1,float px2,float py2,float area_p,
                                         float gx1,float gy1,float gx2,float gy2,float area_g){
#pragma clang fp contract(off)
  float ix = fminf(px2,gx2) - fmaxf(px1,gx1); ix = fmaxf(ix,0.0f);
  float iy = fminf(py2,gy2) - fmaxf(py1,gy1); iy = fmaxf(iy,0.0f);
  float inter = ix*iy;
  return inter / (area_p + area_g - inter);
}

// K1a: for each (b,g), best_priory_idx = first argmax over priors.
__global__ __launch_bounds__(256) void k_bestprior(
    const float* __restrict__ priors, const float* __restrict__ truth,
    int* __restrict__ bestp, int B, int P, int G)
{
#pragma clang fp contract(off)
  const int SUB = 8;
  int b = blockIdx.x / SUB, sub = blockIdx.x % SUB;
  int lane = threadIdx.x & 63, wv = threadIdx.x >> 6;
  int slot = sub*4 + wv;              // 0..31 wave slots per batch
  for (int g = slot; g < G; g += SUB*4) {
    const float* t = truth + ((long)b*G + g)*5;
    float gx1=t[0], gy1=t[1], gx2=t[2], gy2=t[3];
    float ag = (gx2-gx1)*(gy2-gy1);
    unsigned long long best = 0ull;
    for (int p = lane; p < P; p += 64) {
      float4 pr = ((const float4*)priors)[p];
      float px1 = pr.x - 0.5f*pr.z, py1 = pr.y - 0.5f*pr.w;
      float px2 = pr.x + 0.5f*pr.z, py2 = pr.y + 0.5f*pr.w;
      float ap = (px2-px1)*(py2-py1);
      float v = iou_one(px1,py1,px2,py2,ap, gx1,gy1,gx2,gy2,ag);
      unsigned long long key = ((unsigned long long)__float_as_uint(v)<<32) | (unsigned)(P-1-p);
      if (key > best) best = key;
    }
    for (int o=32;o;o>>=1){
      unsigned lo = __shfl_xor((unsigned)best, o);
      unsigned hi = __shfl_xor((unsigned)(best>>32), o);
      unsigned long long other = ((unsigned long long)hi<<32)|lo;
      if (other > best) best = other;
    }
    if (lane==0) bestp[(long)b*G + g] = P - 1 - (int)(unsigned)(best & 0xffffffffu);
  }
}

// K1b: per-prior best gt (first-max), forced overrides (last g wins),
// conf_t, and fused smooth-L1 (positives only).
__global__ __launch_bounds__(256) void k_match(
    const float* __restrict__ pred_loc, const float* __restrict__ priors,
    const float* __restrict__ truth, const int* __restrict__ bestp,
    int* __restrict__ conf_t, int* __restrict__ num_pos, float* __restrict__ accum,
    int B, int P, int G)
{
#pragma clang fp contract(off)
  const int SUB = 8;
  int b = blockIdx.x / SUB, sub = blockIdx.x % SUB;
  int tid = threadIdx.x;
  __shared__ float s_tb[MAXG*5];
  __shared__ float s_ag[MAXG];
  __shared__ int   s_bp[MAXG];
  __shared__ float s_rf[4];
  __shared__ int   s_ri[4];
  for (int i = tid; i < G*5; i += 256) s_tb[i] = truth[(long)b*G*5 + i];
  if (tid < G) s_bp[tid] = bestp[(long)b*G + tid];
  __syncthreads();
  if (tid < G) {
    float x1=s_tb[tid*5], y1=s_tb[tid*5+1], x2=s_tb[tid*5+2], y2=s_tb[tid*5+3];
    s_ag[tid] = (x2-x1)*(y2-y1);
  }
  __syncthreads();
  int chunk = (P + SUB - 1)/SUB;
  int p0 = sub*chunk, p1 = min(p0+chunk, P);
  float lacc = 0.f; int pcnt = 0;
  for (int p = p0 + tid; p < p1; p += 256) {
    float4 pr = ((const float4*)priors)[p];
    float px1 = pr.x - 0.5f*pr.z, py1 = pr.y - 0.5f*pr.w;
    float px2 = pr.x + 0.5f*pr.z, py2 = pr.y + 0.5f*pr.w;
    float ap = (px2-px1)*(py2-py1);
    float bv = -1.0f; int bg = 0;
    for (int g = 0; g < G; ++g) {
      float v = iou_one(px1,py1,px2,py2,ap,
                        s_tb[g*5],s_tb[g*5+1],s_tb[g*5+2],s_tb[g*5+3], s_ag[g]);
      if (v > bv) { bv = v; bg = g; }       // first-max = np.argmax semantics
    }
    float ov = bv; int gi = bg;
    for (int g = 0; g < G; ++g) if (s_bp[g] == p) { ov = 2.0f; gi = g; }  // last wins
    float lb = s_tb[gi*5+4];
    int conf = (ov < 0.5f) ? 0 : (int)(lb + 1.0f);
    conf_t[(long)b*P + p] = conf;
    if (conf > 0) {
      pcnt++;
      float mx1=s_tb[gi*5], my1=s_tb[gi*5+1], mx2=s_tb[gi*5+2], my2=s_tb[gi*5+3];
      float l0 = ((mx1+mx2)*0.5f - pr.x)/pr.z;
      float l1 = ((my1+my2)*0.5f - pr.y)/pr.w;
      float l2 = __logf((mx2-mx1)/pr.z);
      float l3 = __logf((my2-my1)/pr.w);
      float4 pv = *((const float4*)(pred_loc + ((long)b*P + p)*4));
      float d, s = 0.f;
      d = fabsf(pv.x - l0); s += d < 1.f ? 0.5f*d*d : d - 0.5f;
      d = fabsf(pv.y - l1); s += d < 1.f ? 0.5f*d*d : d - 0.5f;
      d = fabsf(pv.z - l2); s += d < 1.f ? 0.5f*d*d : d - 0.5f;
      d = fabsf(pv.w - l3); s += d < 1.f ? 0.5f*d*d : d - 0.5f;
      lacc += s;
    }
  }
  int lane = tid & 63, wv = tid >> 6;
  for (int o=32;o;o>>=1){ lacc += __shfl_xor(lacc,o); pcnt += __shfl_xor(pcnt,o); }
  if (lane==0){ s_rf[wv]=lacc; s_ri[wv]=pcnt; }
  __syncthreads();
  if (tid==0){
    atomicAdd(&accum[0], s_rf[0]+s_rf[1]+s_rf[2]+s_rf[3]);
    atomicAdd(&num_pos[b], s_ri[0]+s_ri[1]+s_ri[2]+s_ri[3]);
  }
}

// K2: one wave per (b,p) row: lse = max + log(sum exp(x-max)), ce = lse - x[conf_t].
__global__ __launch_bounds__(256) void k_ce(
  const float* __restrict__ pred_conf, const int* __restrict__ conf_t,
  float* __restrict__ ce, float* __restrict__ accum, long rows, int C)
{
  const int lane = threadIdx.x & 63;
  const int wv = threadIdx.x >> 6;
  long wave = (long)blockIdx.x * 4 + wv;
  long nw = (long)gridDim.x * 4;
  float pacc = 0.f;
  for (long row = wave; row < rows; row += nw) {
    const float* cp = pred_conf + row * (long)C;
    float x0 = (lane      < C) ? cp[lane]      : -INFINITY;
    float x1 = (64 + lane < C) ? cp[64 + lane] : -INFINITY;
    float m = fmaxf(x0, x1);
    for (int o = 32; o; o >>= 1) m = fmaxf(m, __shfl_xor(m, o));
    float s = __expf(x0 - m) + __expf(x1 - m);   // exp(-inf)=0 handles masked lanes
    for (int o = 32; o; o >>= 1) s += __shfl_xor(s, o);
    float lse = __logf(s) + m;
    int ct = conf_t[row];
    float tA = __shfl(x0, ct & 63);
    float tB = __shfl(x1, (ct - 64) & 63);
    float cev = lse - (ct < 64 ? tA : tB);
    if (lane == 0) { ce[row] = cev; if (ct > 0) pacc += cev; }
  }
  __shared__ float s_f[4];
  if (lane == 0) s_f[wv] = pacc;
  __syncthreads();
  if (threadIdx.x == 0) atomicAdd(&accum[1], s_f[0]+s_f[1]+s_f[2]+s_f[3]);
}

// K3: quirky negative mask. neg contribution = sum over j<num_neg of
// loss_mine[rank(j)] where rank(j) = stable ascending rank of loss_mine[j].
// Zero-class (loss_mine==0, i.e. positives + exact-zero ce) handled analytically
// via a bitmask prefix (stable ranks by index). Nonzero elements ranked by a
// 16384-bin counting sort; contribution gathered straight from s_bits.
__global__ __launch_bounds__(1024) void k_negsel(
    const float* __restrict__ ce, const int* __restrict__ conf_t,
    const int* __restrict__ num_pos, float* __restrict__ accum, int P)
{
  const int b = blockIdx.x;
  const int tid = threadIdx.x;
  const int lane = tid & 63, wv = tid >> 6;
  __shared__ unsigned s_bits[MAXP];
  __shared__ unsigned s_hist[NBINS];
  __shared__ unsigned short s_grp[MAXP];
  __shared__ unsigned long long s_zw[NZW];
  __shared__ int s_zp[NZW];
  __shared__ unsigned s_wsum[16];
  __shared__ float s_facc[16];
  __shared__ int s_nz;

  const int NW = (P + 63) >> 6;
  long base = (long)b * P;
  for (int p = tid; p < P; p += 1024) {
    int ct = conf_t[base + p];
    float v = ce[base + p];
    s_bits[p] = (ct > 0) ? 0u : __float_as_uint(v);   // loss_mine bits (>=0, monotone)
  }
  for (int i = tid; i < NBINS; i += 1024) s_hist[i] = 0;
  __syncthreads();
  // zero-mask words (ballot) + nonzero histogram
  int Pr = (P + 1023) & ~1023;
  for (int p = tid; p < Pr; p += 1024) {
    unsigned bits = (p < P) ? s_bits[p] : 1u;   // out-of-range: "nonzero", no hist
    unsigned long long mask = __ballot(bits == 0u);
    int w = p >> 6;
    if (lane == 0 && w < NW) s_zw[w] = mask;
    if (p < P && bits != 0u) atomicAdd(&s_hist[bits >> 17], 1u);
  }
  __syncthreads();
  // exclusive scan over NBINS (16 bins/thread)
  unsigned loc[16]; unsigned tot = 0;
  int hbase = tid * 16;
#pragma unroll
  for (int i = 0; i < 16; ++i) { loc[i] = s_hist[hbase + i]; tot += loc[i]; }
  unsigned incl = tot;
  for (int o = 1; o < 64; o <<= 1) {
    unsigned n = __shfl_up(incl, o);
    if (lane >= o) incl += n;
  }
  if (lane == 63) s_wsum[wv] = incl;
  __syncthreads();
  if (tid == 0) {
    unsigned r = 0;
    for (int i = 0; i < 16; ++i) { unsigned t = s_wsum[i]; s_wsum[i] = r; r += t; }
  }
  __syncthreads();
  unsigned run = incl - tot + s_wsum[wv];
#pragma unroll
  for (int i = 0; i < 16; ++i) { s_hist[hbase + i] = run; run += loc[i]; }
  // wave 0: zero-class prefix over NW (<=192) mask words
  if (wv == 0) {
    int v0 = (lane < NW)       ? __popcll(s_zw[lane])       : 0;
    int v1 = (64 + lane < NW)  ? __popcll(s_zw[64 + lane])  : 0;
    int v2 = (128 + lane < NW) ? __popcll(s_zw[128 + lane]) : 0;
    int s0 = v0, s1 = v1, s2 = v2;
    for (int o = 1; o < 64; o <<= 1) {
      int n0 = __shfl_up(s0, o), n1 = __shfl_up(s1, o), n2 = __shfl_up(s2, o);
      if (lane >= o) { s0 += n0; s1 += n1; s2 += n2; }
    }
    int t0 = __shfl(s0, 63), t1 = __shfl(s1, 63), t2 = __shfl(s2, 63);
    if (lane < NW)       s_zp[lane]       = s0 - v0;
    if (64 + lane < NW)  s_zp[64 + lane]  = t0 + s1 - v1;
    if (128 + lane < NW) s_zp[128 + lane] = t0 + t1 + s2 - v2;
    if (lane == 0) s_nz = t0 + t1 + t2;
  }
  __syncthreads();
  // scatter nonzero into bucket-grouped order
  for (int p = tid; p < P; p += 1024) {
    unsigned bits = s_bits[p];
    if (bits != 0u) {
      unsigned slot = atomicAdd(&s_hist[bits >> 17], 1u);
      s_grp[slot] = (unsigned short)p;
    }
  }
  __syncthreads();
  int npos = num_pos[b];
  int nneg = min(3 * npos, P - 1);
  int nz = s_nz;
  float acc = 0.f;
  for (int j = tid; j < nneg; j += 1024) {
    unsigned bj = s_bits[j];
    int rk;
    if (bj == 0u) {
      int w = j >> 6;
      unsigned long long below = (j & 63) ? (s_zw[w] & ((1ull << (j & 63)) - 1ull)) : 0ull;
      rk = s_zp[w] + __popcll(below);
    } else {
      unsigned bu = bj >> 17;
      unsigned start = bu ? s_hist[bu - 1] : 0u;   // after scatter: hist[x] = end of x
      unsigned end = s_hist[bu];
      unsigned cnt = 0;
#pragma unroll 4
      for (unsigned t = start; t < end; ++t) {
        int k = s_grp[t];
        unsigned bk = s_bits[k];
        cnt += (bk < bj) || (bk == bj && k < j);
      }
      rk = nz + (int)(start + cnt);                // stable ascending rank of j
    }
    acc += __uint_as_float(s_bits[rk]);            // = ce[rk] if neg, 0 if pos
  }
  for (int o=32;o;o>>=1) acc += __shfl_xor(acc,o);
  if (lane==0) s_facc[wv]=acc;
  __syncthreads();
  if (tid==0){ float f=0; for(int i=0;i<16;i++) f+=s_facc[i]; atomicAdd(&accum[2], f); }
}

__global__ void k_final(const int* __restrict__ num_pos, const float* __restrict__ accum,
                        float* __restrict__ out, int B)
{
  int s = 0;
  for (int i = threadIdx.x; i < B; i += 64) s += num_pos[i];
  for (int o=32;o;o>>=1) s += __shfl_xor(s,o);
  if (threadIdx.x == 0) {
    float N = (float)s;
    out[0] = accum[0] / N;
    out[1] = (accum[1] + accum[2]) / N;
  }
}

extern "C" void kernel_launch(void* const* d_in, const int* in_sizes, int n_in,
                              void* d_out, int out_size, void* d_ws, size_t ws_size,
                              hipStream_t stream)
{
  const float* pred_conf = (const float*)d_in[0];
  const float* pred_loc  = (const float*)d_in[1];
  const float* priors    = (const float*)d_in[2];
  const float* truth     = (const float*)d_in[3];
  int  P  = in_sizes[2] / 4;
  long BP = in_sizes[1] / 4;          // B*P
  int  B  = (int)(BP / P);
  int  C  = (int)(in_sizes[0] / BP);
  int  G  = in_sizes[3] / (B * 5);

  char* ws = (char*)d_ws;
  size_t off = 0;
  int*   conf_t  = (int*)(ws + off);   off += sizeof(int)   * (size_t)BP;
  float* ce      = (float*)(ws + off); off += sizeof(float) * (size_t)BP;
  int*   bestp   = (int*)(ws + off);   off += sizeof(int)   * (size_t)B * G;
  int*   num_pos = (int*)(ws + off);   off += sizeof(int)   * (size_t)B;
  float* accum   = (float*)(ws + off); off += 4 * sizeof(float);

  // zero num_pos + accum (contiguous) every launch
  hipMemsetAsync(num_pos, 0, sizeof(int) * (size_t)B + 4 * sizeof(float), stream);

  k_bestprior<<<B * 8, 256, 0, stream>>>(priors, truth, bestp, B, P, G);
  k_match    <<<B * 8, 256, 0, stream>>>(pred_loc, priors, truth, bestp,
                                         conf_t, num_pos, accum, B, P, G);
  k_ce       <<<2048, 256, 0, stream>>>(pred_conf, conf_t, ce, accum, BP, C);
  k_negsel   <<<B, 1024, 0, stream>>>(ce, conf_t, num_pos, accum, P);
  k_final    <<<1, 64, 0, stream>>>(num_pos, accum, (float*)d_out, B);
}

// Round 3
// 253.441 us; speedup vs baseline: 1.7647x; 1.1540x over previous
//
#include <hip/hip_runtime.h>
#include <math.h>

#define MAXP 8732
#define MAXG 64
#define NBINS 16384   // float_bits >> 17 (sign+exp+6 mantissa bits)
#define NZW   ((MAXP + 63) / 64)

// IoU with the exact op order of the numpy reference; contraction off so the
// decision-critical values (argmax ties, <0.5 threshold) match numpy bit-for-bit.
__device__ __forceinline__ float iou_one(float px1,float py1,float px2,float py2,float area_p,
                                         float gx1,float gy1,float gx2,float gy2,float area_g){
#pragma clang fp contract(off)
  float ix = fminf(px2,gx2) - fmaxf(px1,gx1); ix = fmaxf(ix,0.0f);
  float iy = fminf(py2,gy2) - fmaxf(py1,gy1); iy = fmaxf(iy,0.0f);
  float inter = ix*iy;
  return inter / (area_p + area_g - inter);
}

// K1a: for each (b,g), best_priory_idx = first argmax over priors.
// Writes override map: over[b*P + p_best] = max g (last-wins == max-wins).
__global__ __launch_bounds__(256) void k_bestprior(
    const float* __restrict__ priors, const float* __restrict__ truth,
    int* __restrict__ over, int B, int P, int G)
{
#pragma clang fp contract(off)
  const int SUB = 8;
  int b = blockIdx.x / SUB, sub = blockIdx.x % SUB;
  int lane = threadIdx.x & 63, wv = threadIdx.x >> 6;
  int slot = sub*4 + wv;              // 0..31 wave slots per batch
  for (int g = slot; g < G; g += SUB*4) {
    const float* t = truth + ((long)b*G + g)*5;
    float gx1=t[0], gy1=t[1], gx2=t[2], gy2=t[3];
    float ag = (gx2-gx1)*(gy2-gy1);
    unsigned long long best = 0ull;
    for (int p = lane; p < P; p += 64) {
      float4 pr = ((const float4*)priors)[p];
      float px1 = pr.x - 0.5f*pr.z, py1 = pr.y - 0.5f*pr.w;
      float px2 = pr.x + 0.5f*pr.z, py2 = pr.y + 0.5f*pr.w;
      float ap = (px2-px1)*(py2-py1);
      float v = iou_one(px1,py1,px2,py2,ap, gx1,gy1,gx2,gy2,ag);
      unsigned long long key = ((unsigned long long)__float_as_uint(v)<<32) | (unsigned)(P-1-p);
      if (key > best) best = key;
    }
    for (int o=32;o;o>>=1){
      unsigned lo = __shfl_xor((unsigned)best, o);
      unsigned hi = __shfl_xor((unsigned)(best>>32), o);
      unsigned long long other = ((unsigned long long)hi<<32)|lo;
      if (other > best) best = other;
    }
    if (lane==0) {
      int pbest = P - 1 - (int)(unsigned)(best & 0xffffffffu);
      atomicMax(&over[(long)b*P + pbest], g);
    }
  }
}

// K1b: per-prior best gt (first-max), forced overrides (from over[]),
// conf_t, and fused smooth-L1 (positives only).
__global__ __launch_bounds__(256) void k_match(
    const float* __restrict__ pred_loc, const float* __restrict__ priors,
    const float* __restrict__ truth, const int* __restrict__ over,
    int* __restrict__ conf_t, int* __restrict__ num_pos, float* __restrict__ accum,
    int B, int P, int G)
{
#pragma clang fp contract(off)
  const int SUB = 8;
  int b = blockIdx.x / SUB, sub = blockIdx.x % SUB;
  int tid = threadIdx.x;
  __shared__ float s_tb[MAXG*5];
  __shared__ float s_ag[MAXG];
  __shared__ float s_rf[4];
  __shared__ int   s_ri[4];
  for (int i = tid; i < G*5; i += 256) s_tb[i] = truth[(long)b*G*5 + i];
  __syncthreads();
  if (tid < G) {
    float x1=s_tb[tid*5], y1=s_tb[tid*5+1], x2=s_tb[tid*5+2], y2=s_tb[tid*5+3];
    s_ag[tid] = (x2-x1)*(y2-y1);
  }
  __syncthreads();
  int chunk = (P + SUB - 1)/SUB;
  int p0 = sub*chunk, p1 = min(p0+chunk, P);
  float lacc = 0.f; int pcnt = 0;
  for (int p = p0 + tid; p < p1; p += 256) {
    float4 pr = ((const float4*)priors)[p];
    float px1 = pr.x - 0.5f*pr.z, py1 = pr.y - 0.5f*pr.w;
    float px2 = pr.x + 0.5f*pr.z, py2 = pr.y + 0.5f*pr.w;
    float ap = (px2-px1)*(py2-py1);
    float bv = -1.0f; int bg = 0;
    for (int g = 0; g < G; ++g) {
      float v = iou_one(px1,py1,px2,py2,ap,
                        s_tb[g*5],s_tb[g*5+1],s_tb[g*5+2],s_tb[g*5+3], s_ag[g]);
      if (v > bv) { bv = v; bg = g; }       // first-max = np.argmax semantics
    }
    float ov = bv; int gi = bg;
    int ovg = over[(long)b*P + p];
    if (ovg >= 0) { ov = 2.0f; gi = ovg; }  // forced match (max g == last wins)
    float lb = s_tb[gi*5+4];
    int conf = (ov < 0.5f) ? 0 : (int)(lb + 1.0f);
    conf_t[(long)b*P + p] = conf;
    if (conf > 0) {
      pcnt++;
      float mx1=s_tb[gi*5], my1=s_tb[gi*5+1], mx2=s_tb[gi*5+2], my2=s_tb[gi*5+3];
      float l0 = ((mx1+mx2)*0.5f - pr.x)/pr.z;
      float l1 = ((my1+my2)*0.5f - pr.y)/pr.w;
      float l2 = __logf((mx2-mx1)/pr.z);
      float l3 = __logf((my2-my1)/pr.w);
      float4 pv = *((const float4*)(pred_loc + ((long)b*P + p)*4));
      float d, s = 0.f;
      d = fabsf(pv.x - l0); s += d < 1.f ? 0.5f*d*d : d - 0.5f;
      d = fabsf(pv.y - l1); s += d < 1.f ? 0.5f*d*d : d - 0.5f;
      d = fabsf(pv.z - l2); s += d < 1.f ? 0.5f*d*d : d - 0.5f;
      d = fabsf(pv.w - l3); s += d < 1.f ? 0.5f*d*d : d - 0.5f;
      lacc += s;
    }
  }
  int lane = tid & 63, wv = tid >> 6;
  for (int o=32;o;o>>=1){ lacc += __shfl_xor(lacc,o); pcnt += __shfl_xor(pcnt,o); }
  if (lane==0){ s_rf[wv]=lacc; s_ri[wv]=pcnt; }
  __syncthreads();
  if (tid==0){
    atomicAdd(&accum[0], s_rf[0]+s_rf[1]+s_rf[2]+s_rf[3]);
    atomicAdd(&num_pos[b], s_ri[0]+s_ri[1]+s_ri[2]+s_ri[3]);
  }
}

// K2: 16 lanes per row, 4 rows per wave per iteration. Each lane holds 6
// elements; 4-step quarter-wave shuffles amortized across 4 rows.
__global__ __launch_bounds__(256) void k_ce(
  const float* __restrict__ pred_conf, const int* __restrict__ conf_t,
  float* __restrict__ ce, float* __restrict__ accum, long rows, int C)
{
  const int tid = threadIdx.x;
  const int lane = tid & 63;
  const int wv = tid >> 6;
  const int g = lane >> 4;        // row group 0..3 within wave
  const int l = lane & 15;        // lane within group
  long wave = (long)blockIdx.x * 4 + wv;
  long nw = (long)gridDim.x * 4;
  float pacc = 0.f;
  for (long r0 = wave * 4; r0 < rows; r0 += nw * 4) {
    long row = r0 + g;
    bool valid = row < rows;
    const float* cp = pred_conf + (valid ? row : 0) * (long)C;
    float x0 = cp[l];
    float x1 = cp[l + 16];
    float x2 = cp[l + 32];
    float x3 = cp[l + 48];
    float x4 = cp[l + 64];
    float x5 = (l == 0) ? cp[80] : -INFINITY;
    float m = fmaxf(fmaxf(fmaxf(x0,x1),fmaxf(x2,x3)),fmaxf(x4,x5));
    for (int o = 8; o; o >>= 1) m = fmaxf(m, __shfl_xor(m, o));
    float s = __expf(x0-m)+__expf(x1-m)+__expf(x2-m)
            + __expf(x3-m)+__expf(x4-m)+__expf(x5-m);   // exp(-inf)=0
    int ct = valid ? conf_t[row] : 0;
    float tv = (ct == l      ? x0 : 0.f)
             + (ct == l+16   ? x1 : 0.f)
             + (ct == l+32   ? x2 : 0.f)
             + (ct == l+48   ? x3 : 0.f)
             + (ct == l+64   ? x4 : 0.f)
             + ((ct == 80 && l == 0) ? x5 : 0.f);
    for (int o = 8; o; o >>= 1) { s += __shfl_xor(s, o); tv += __shfl_xor(tv, o); }
    float cev = __logf(s) + m - tv;
    if (valid && l == 0) { ce[row] = cev; if (ct > 0) pacc += cev; }
  }
  for (int o = 32; o; o >>= 1) pacc += __shfl_xor(pacc, o);
  __shared__ float s_f[4];
  if (lane == 0) s_f[wv] = pacc;
  __syncthreads();
  if (threadIdx.x == 0) atomicAdd(&accum[1], s_f[0]+s_f[1]+s_f[2]+s_f[3]);
}

// K3: quirky negative mask. neg contribution = sum over j<num_neg of
// loss_mine[rank(j)] where rank(j) = stable ascending rank of loss_mine[j].
// Zero-class handled analytically via ballot-prefix; nonzero via 16384-bin
// counting sort with within-bucket stable-rank scan.
__global__ __launch_bounds__(1024) void k_negsel(
    const float* __restrict__ ce, const int* __restrict__ conf_t,
    const int* __restrict__ num_pos, float* __restrict__ accum, int P)
{
  const int b = blockIdx.x;
  const int tid = threadIdx.x;
  const int lane = tid & 63, wv = tid >> 6;
  __shared__ unsigned s_bits[MAXP];
  __shared__ unsigned s_hist[NBINS];
  __shared__ unsigned short s_grp[MAXP];
  __shared__ unsigned long long s_zw[NZW];
  __shared__ int s_zp[NZW];
  __shared__ unsigned s_wsum[16];
  __shared__ float s_facc[16];
  __shared__ int s_nz;

  const int NW = (P + 63) >> 6;
  long base = (long)b * P;
  for (int p = tid; p < P; p += 1024) {
    int ct = conf_t[base + p];
    float v = ce[base + p];
    s_bits[p] = (ct > 0) ? 0u : __float_as_uint(v);   // loss_mine bits (>=0, monotone)
  }
  for (int i = tid; i < NBINS; i += 1024) s_hist[i] = 0;
  __syncthreads();
  // zero-mask words (ballot) + nonzero histogram
  int Pr = (P + 1023) & ~1023;
  for (int p = tid; p < Pr; p += 1024) {
    unsigned bits = (p < P) ? s_bits[p] : 1u;   // out-of-range: "nonzero", no hist
    unsigned long long mask = __ballot(bits == 0u);
    int w = p >> 6;
    if (lane == 0 && w < NW) s_zw[w] = mask;
    if (p < P && bits != 0u) atomicAdd(&s_hist[bits >> 17], 1u);
  }
  __syncthreads();
  // exclusive scan over NBINS (16 bins/thread)
  unsigned loc[16]; unsigned tot = 0;
  int hbase = tid * 16;
#pragma unroll
  for (int i = 0; i < 16; ++i) { loc[i] = s_hist[hbase + i]; tot += loc[i]; }
  unsigned incl = tot;
  for (int o = 1; o < 64; o <<= 1) {
    unsigned n = __shfl_up(incl, o);
    if (lane >= o) incl += n;
  }
  if (lane == 63) s_wsum[wv] = incl;
  __syncthreads();
  if (tid == 0) {
    unsigned r = 0;
    for (int i = 0; i < 16; ++i) { unsigned t = s_wsum[i]; s_wsum[i] = r; r += t; }
  }
  __syncthreads();
  unsigned run = incl - tot + s_wsum[wv];
#pragma unroll
  for (int i = 0; i < 16; ++i) { s_hist[hbase + i] = run; run += loc[i]; }
  // wave 0: zero-class prefix over NW (<=192) mask words
  if (wv == 0) {
    int v0 = (lane < NW)       ? __popcll(s_zw[lane])       : 0;
    int v1 = (64 + lane < NW)  ? __popcll(s_zw[64 + lane])  : 0;
    int v2 = (128 + lane < NW) ? __popcll(s_zw[128 + lane]) : 0;
    int s0 = v0, s1 = v1, s2 = v2;
    for (int o = 1; o < 64; o <<= 1) {
      int n0 = __shfl_up(s0, o), n1 = __shfl_up(s1, o), n2 = __shfl_up(s2, o);
      if (lane >= o) { s0 += n0; s1 += n1; s2 += n2; }
    }
    int t0 = __shfl(s0, 63), t1 = __shfl(s1, 63), t2 = __shfl(s2, 63);
    if (lane < NW)       s_zp[lane]       = s0 - v0;
    if (64 + lane < NW)  s_zp[64 + lane]  = t0 + s1 - v1;
    if (128 + lane < NW) s_zp[128 + lane] = t0 + t1 + s2 - v2;
    if (lane == 0) s_nz = t0 + t1 + t2;
  }
  __syncthreads();
  // scatter nonzero into bucket-grouped order
  for (int p = tid; p < P; p += 1024) {
    unsigned bits = s_bits[p];
    if (bits != 0u) {
      unsigned slot = atomicAdd(&s_hist[bits >> 17], 1u);
      s_grp[slot] = (unsigned short)p;
    }
  }
  __syncthreads();
  int npos = num_pos[b];
  int nneg = min(3 * npos, P - 1);
  int nz = s_nz;
  float acc = 0.f;
  for (int j = tid; j < nneg; j += 1024) {
    unsigned bj = s_bits[j];
    int rk;
    if (bj == 0u) {
      int w = j >> 6;
      unsigned long long below = (j & 63) ? (s_zw[w] & ((1ull << (j & 63)) - 1ull)) : 0ull;
      rk = s_zp[w] + __popcll(below);
    } else {
      unsigned bu = bj >> 17;
      unsigned start = bu ? s_hist[bu - 1] : 0u;   // after scatter: hist[x] = end of x
      unsigned end = s_hist[bu];
      unsigned cnt = 0;
#pragma unroll 4
      for (unsigned t = start; t < end; ++t) {
        int k = s_grp[t];
        unsigned bk = s_bits[k];
        cnt += (bk < bj) || (bk == bj && k < j);
      }
      rk = nz + (int)(start + cnt);                // stable ascending rank of j
    }
    acc += __uint_as_float(s_bits[rk]);            // = ce[rk] if neg, 0 if pos
  }
  for (int o=32;o;o>>=1) acc += __shfl_xor(acc,o);
  if (lane==0) s_facc[wv]=acc;
  __syncthreads();
  if (tid==0){ float f=0; for(int i=0;i<16;i++) f+=s_facc[i]; atomicAdd(&accum[2], f); }
}

__global__ void k_final(const int* __restrict__ num_pos, const float* __restrict__ accum,
                        float* __restrict__ out, int B)
{
  int s = 0;
  for (int i = threadIdx.x; i < B; i += 64) s += num_pos[i];
  for (int o=32;o;o>>=1) s += __shfl_xor(s,o);
  if (threadIdx.x == 0) {
    float N = (float)s;
    out[0] = accum[0] / N;
    out[1] = (accum[1] + accum[2]) / N;
  }
}

extern "C" void kernel_launch(void* const* d_in, const int* in_sizes, int n_in,
                              void* d_out, int out_size, void* d_ws, size_t ws_size,
                              hipStream_t stream)
{
  const float* pred_conf = (const float*)d_in[0];
  const float* pred_loc  = (const float*)d_in[1];
  const float* priors    = (const float*)d_in[2];
  const float* truth     = (const float*)d_in[3];
  int  P  = in_sizes[2] / 4;
  long BP = in_sizes[1] / 4;          // B*P
  int  B  = (int)(BP / P);
  int  C  = (int)(in_sizes[0] / BP);
  int  G  = in_sizes[3] / (B * 5);

  char* ws = (char*)d_ws;
  size_t off = 0;
  int*   conf_t  = (int*)(ws + off);   off += sizeof(int)   * (size_t)BP;
  float* ce      = (float*)(ws + off); off += sizeof(float) * (size_t)BP;
  int*   over    = (int*)(ws + off);   off += sizeof(int)   * (size_t)BP;
  int*   num_pos = (int*)(ws + off);   off += sizeof(int)   * (size_t)B;
  float* accum   = (float*)(ws + off); off += 4 * sizeof(float);

  // over = -1 everywhere; num_pos + accum (contiguous) = 0
  hipMemsetAsync(over, 0xFF, sizeof(int) * (size_t)BP, stream);
  hipMemsetAsync(num_pos, 0, sizeof(int) * (size_t)B + 4 * sizeof(float), stream);

  k_bestprior<<<B * 8, 256, 0, stream>>>(priors, truth, over, B, P, G);
  k_match    <<<B * 8, 256, 0, stream>>>(pred_loc, priors, truth, over,
                                         conf_t, num_pos, accum, B, P, G);
  k_ce       <<<4096, 256, 0, stream>>>(pred_conf, conf_t, ce, accum, BP, C);
  k_negsel   <<<B, 1024, 0, stream>>>(ce, conf_t, num_pos, accum, P);
  k_final    <<<1, 64, 0, stream>>>(num_pos, accum, (float*)d_out, B);
}

// Round 4
// 252.385 us; speedup vs baseline: 1.7721x; 1.0042x over previous
//
#include <hip/hip_runtime.h>
#include <math.h>

#define MAXP 8732
#define MAXG 64
#define NBINS 16384   // float_bits >> 17 (sign+exp+6 mantissa bits)
#define NZW   ((MAXP + 63) / 64)

// IoU with the exact op order of the numpy reference; contraction off so the
// decision-critical values (argmax ties, <0.5 threshold) match numpy bit-for-bit.
__device__ __forceinline__ float iou_one(float px1,float py1,float px2,float py2,float area_p,
                                         float gx1,float gy1,float gx2,float gy2,float area_g){
#pragma clang fp contract(off)
  float ix = fminf(px2,gx2) - fmaxf(px1,gx1); ix = fmaxf(ix,0.0f);
  float iy = fminf(py2,gy2) - fmaxf(py1,gy1); iy = fmaxf(iy,0.0f);
  float inter = ix*iy;
  return inter / (area_p + area_g - inter);
}

// K0: workspace init (replaces hipMemsetAsync — the runtime fill kernel cost
// ~102 us/launch under graph capture). over=-1, num_pos=0, accum=0.
__global__ __launch_bounds__(256) void k_init(
    int* __restrict__ over, int* __restrict__ num_pos, float* __restrict__ accum,
    long n_over, int B)
{
  long i = (long)blockIdx.x * 256 + threadIdx.x;
  long stride = (long)gridDim.x * 256;
  for (long p = i; p < n_over; p += stride) over[p] = -1;
  if (blockIdx.x == 0) {
    for (int j = threadIdx.x; j < B; j += 256) num_pos[j] = 0;
    if (threadIdx.x < 4) accum[threadIdx.x] = 0.f;
  }
}

// K1a: for each (b,g), best_priory_idx = first argmax over priors.
// Writes override map: over[b*P + p_best] = max g (last-wins == max-wins).
__global__ __launch_bounds__(256) void k_bestprior(
    const float* __restrict__ priors, const float* __restrict__ truth,
    int* __restrict__ over, int B, int P, int G)
{
#pragma clang fp contract(off)
  const int SUB = 8;
  int b = blockIdx.x / SUB, sub = blockIdx.x % SUB;
  int lane = threadIdx.x & 63, wv = threadIdx.x >> 6;
  int slot = sub*4 + wv;              // 0..31 wave slots per batch
  for (int g = slot; g < G; g += SUB*4) {
    const float* t = truth + ((long)b*G + g)*5;
    float gx1=t[0], gy1=t[1], gx2=t[2], gy2=t[3];
    float ag = (gx2-gx1)*(gy2-gy1);
    unsigned long long best = 0ull;
    for (int p = lane; p < P; p += 64) {
      float4 pr = ((const float4*)priors)[p];
      float px1 = pr.x - 0.5f*pr.z, py1 = pr.y - 0.5f*pr.w;
      float px2 = pr.x + 0.5f*pr.z, py2 = pr.y + 0.5f*pr.w;
      float ap = (px2-px1)*(py2-py1);
      float v = iou_one(px1,py1,px2,py2,ap, gx1,gy1,gx2,gy2,ag);
      unsigned long long key = ((unsigned long long)__float_as_uint(v)<<32) | (unsigned)(P-1-p);
      if (key > best) best = key;
    }
    for (int o=32;o;o>>=1){
      unsigned lo = __shfl_xor((unsigned)best, o);
      unsigned hi = __shfl_xor((unsigned)(best>>32), o);
      unsigned long long other = ((unsigned long long)hi<<32)|lo;
      if (other > best) best = other;
    }
    if (lane==0) {
      int pbest = P - 1 - (int)(unsigned)(best & 0xffffffffu);
      atomicMax(&over[(long)b*P + pbest], g);
    }
  }
}

// K1b: per-prior best gt (first-max), forced overrides (from over[]),
// conf_t, and fused smooth-L1 (positives only).
__global__ __launch_bounds__(256) void k_match(
    const float* __restrict__ pred_loc, const float* __restrict__ priors,
    const float* __restrict__ truth, const int* __restrict__ over,
    int* __restrict__ conf_t, int* __restrict__ num_pos, float* __restrict__ accum,
    int B, int P, int G)
{
#pragma clang fp contract(off)
  const int SUB = 8;
  int b = blockIdx.x / SUB, sub = blockIdx.x % SUB;
  int tid = threadIdx.x;
  __shared__ float s_tb[MAXG*5];
  __shared__ float s_ag[MAXG];
  __shared__ float s_rf[4];
  __shared__ int   s_ri[4];
  for (int i = tid; i < G*5; i += 256) s_tb[i] = truth[(long)b*G*5 + i];
  __syncthreads();
  if (tid < G) {
    float x1=s_tb[tid*5], y1=s_tb[tid*5+1], x2=s_tb[tid*5+2], y2=s_tb[tid*5+3];
    s_ag[tid] = (x2-x1)*(y2-y1);
  }
  __syncthreads();
  int chunk = (P + SUB - 1)/SUB;
  int p0 = sub*chunk, p1 = min(p0+chunk, P);
  float lacc = 0.f; int pcnt = 0;
  for (int p = p0 + tid; p < p1; p += 256) {
    float4 pr = ((const float4*)priors)[p];
    float px1 = pr.x - 0.5f*pr.z, py1 = pr.y - 0.5f*pr.w;
    float px2 = pr.x + 0.5f*pr.z, py2 = pr.y + 0.5f*pr.w;
    float ap = (px2-px1)*(py2-py1);
    float bv = -1.0f; int bg = 0;
    for (int g = 0; g < G; ++g) {
      float v = iou_one(px1,py1,px2,py2,ap,
                        s_tb[g*5],s_tb[g*5+1],s_tb[g*5+2],s_tb[g*5+3], s_ag[g]);
      if (v > bv) { bv = v; bg = g; }       // first-max = np.argmax semantics
    }
    float ov = bv; int gi = bg;
    int ovg = over[(long)b*P + p];
    if (ovg >= 0) { ov = 2.0f; gi = ovg; }  // forced match (max g == last wins)
    float lb = s_tb[gi*5+4];
    int conf = (ov < 0.5f) ? 0 : (int)(lb + 1.0f);
    conf_t[(long)b*P + p] = conf;
    if (conf > 0) {
      pcnt++;
      float mx1=s_tb[gi*5], my1=s_tb[gi*5+1], mx2=s_tb[gi*5+2], my2=s_tb[gi*5+3];
      float l0 = ((mx1+mx2)*0.5f - pr.x)/pr.z;
      float l1 = ((my1+my2)*0.5f - pr.y)/pr.w;
      float l2 = __logf((mx2-mx1)/pr.z);
      float l3 = __logf((my2-my1)/pr.w);
      float4 pv = *((const float4*)(pred_loc + ((long)b*P + p)*4));
      float d, s = 0.f;
      d = fabsf(pv.x - l0); s += d < 1.f ? 0.5f*d*d : d - 0.5f;
      d = fabsf(pv.y - l1); s += d < 1.f ? 0.5f*d*d : d - 0.5f;
      d = fabsf(pv.z - l2); s += d < 1.f ? 0.5f*d*d : d - 0.5f;
      d = fabsf(pv.w - l3); s += d < 1.f ? 0.5f*d*d : d - 0.5f;
      lacc += s;
    }
  }
  int lane = tid & 63, wv = tid >> 6;
  for (int o=32;o;o>>=1){ lacc += __shfl_xor(lacc,o); pcnt += __shfl_xor(pcnt,o); }
  if (lane==0){ s_rf[wv]=lacc; s_ri[wv]=pcnt; }
  __syncthreads();
  if (tid==0){
    atomicAdd(&accum[0], s_rf[0]+s_rf[1]+s_rf[2]+s_rf[3]);
    atomicAdd(&num_pos[b], s_ri[0]+s_ri[1]+s_ri[2]+s_ri[3]);
  }
}

// K2: 16 lanes per row, 4 rows per wave per iteration. Each lane holds 6
// elements; 4-step quarter-wave shuffles amortized across 4 rows.
__global__ __launch_bounds__(256) void k_ce(
  const float* __restrict__ pred_conf, const int* __restrict__ conf_t,
  float* __restrict__ ce, float* __restrict__ accum, long rows, int C)
{
  const int tid = threadIdx.x;
  const int lane = tid & 63;
  const int wv = tid >> 6;
  const int g = lane >> 4;        // row group 0..3 within wave
  const int l = lane & 15;        // lane within group
  long wave = (long)blockIdx.x * 4 + wv;
  long nw = (long)gridDim.x * 4;
  float pacc = 0.f;
  for (long r0 = wave * 4; r0 < rows; r0 += nw * 4) {
    long row = r0 + g;
    bool valid = row < rows;
    const float* cp = pred_conf + (valid ? row : 0) * (long)C;
    float x0 = cp[l];
    float x1 = cp[l + 16];
    float x2 = cp[l + 32];
    float x3 = cp[l + 48];
    float x4 = cp[l + 64];
    float x5 = (l == 0) ? cp[80] : -INFINITY;
    float m = fmaxf(fmaxf(fmaxf(x0,x1),fmaxf(x2,x3)),fmaxf(x4,x5));
    for (int o = 8; o; o >>= 1) m = fmaxf(m, __shfl_xor(m, o));
    float s = __expf(x0-m)+__expf(x1-m)+__expf(x2-m)
            + __expf(x3-m)+__expf(x4-m)+__expf(x5-m);   // exp(-inf)=0
    int ct = valid ? conf_t[row] : 0;
    float tv = (ct == l      ? x0 : 0.f)
             + (ct == l+16   ? x1 : 0.f)
             + (ct == l+32   ? x2 : 0.f)
             + (ct == l+48   ? x3 : 0.f)
             + (ct == l+64   ? x4 : 0.f)
             + ((ct == 80 && l == 0) ? x5 : 0.f);
    for (int o = 8; o; o >>= 1) { s += __shfl_xor(s, o); tv += __shfl_xor(tv, o); }
    float cev = __logf(s) + m - tv;
    if (valid && l == 0) { ce[row] = cev; if (ct > 0) pacc += cev; }
  }
  for (int o = 32; o; o >>= 1) pacc += __shfl_xor(pacc, o);
  __shared__ float s_f[4];
  if (lane == 0) s_f[wv] = pacc;
  __syncthreads();
  if (threadIdx.x == 0) atomicAdd(&accum[1], s_f[0]+s_f[1]+s_f[2]+s_f[3]);
}

// K3: quirky negative mask. neg contribution = sum over j<num_neg of
// loss_mine[rank(j)] where rank(j) = stable ascending rank of loss_mine[j].
// Zero-class handled analytically via ballot-prefix; nonzero via 16384-bin
// counting sort with within-bucket stable-rank scan.
__global__ __launch_bounds__(1024) void k_negsel(
    const float* __restrict__ ce, const int* __restrict__ conf_t,
    const int* __restrict__ num_pos, float* __restrict__ accum, int P)
{
  const int b = blockIdx.x;
  const int tid = threadIdx.x;
  const int lane = tid & 63, wv = tid >> 6;
  __shared__ unsigned s_bits[MAXP];
  __shared__ unsigned s_hist[NBINS];
  __shared__ unsigned short s_grp[MAXP];
  __shared__ unsigned long long s_zw[NZW];
  __shared__ int s_zp[NZW];
  __shared__ unsigned s_wsum[16];
  __shared__ float s_facc[16];
  __shared__ int s_nz;

  const int NW = (P + 63) >> 6;
  long base = (long)b * P;
  for (int p = tid; p < P; p += 1024) {
    int ct = conf_t[base + p];
    float v = ce[base + p];
    s_bits[p] = (ct > 0) ? 0u : __float_as_uint(v);   // loss_mine bits (>=0, monotone)
  }
  for (int i = tid; i < NBINS; i += 1024) s_hist[i] = 0;
  __syncthreads();
  // zero-mask words (ballot) + nonzero histogram
  int Pr = (P + 1023) & ~1023;
  for (int p = tid; p < Pr; p += 1024) {
    unsigned bits = (p < P) ? s_bits[p] : 1u;   // out-of-range: "nonzero", no hist
    unsigned long long mask = __ballot(bits == 0u);
    int w = p >> 6;
    if (lane == 0 && w < NW) s_zw[w] = mask;
    if (p < P && bits != 0u) atomicAdd(&s_hist[bits >> 17], 1u);
  }
  __syncthreads();
  // exclusive scan over NBINS (16 bins/thread)
  unsigned loc[16]; unsigned tot = 0;
  int hbase = tid * 16;
#pragma unroll
  for (int i = 0; i < 16; ++i) { loc[i] = s_hist[hbase + i]; tot += loc[i]; }
  unsigned incl = tot;
  for (int o = 1; o < 64; o <<= 1) {
    unsigned n = __shfl_up(incl, o);
    if (lane >= o) incl += n;
  }
  if (lane == 63) s_wsum[wv] = incl;
  __syncthreads();
  if (tid == 0) {
    unsigned r = 0;
    for (int i = 0; i < 16; ++i) { unsigned t = s_wsum[i]; s_wsum[i] = r; r += t; }
  }
  __syncthreads();
  unsigned run = incl - tot + s_wsum[wv];
#pragma unroll
  for (int i = 0; i < 16; ++i) { s_hist[hbase + i] = run; run += loc[i]; }
  // wave 0: zero-class prefix over NW (<=192) mask words
  if (wv == 0) {
    int v0 = (lane < NW)       ? __popcll(s_zw[lane])       : 0;
    int v1 = (64 + lane < NW)  ? __popcll(s_zw[64 + lane])  : 0;
    int v2 = (128 + lane < NW) ? __popcll(s_zw[128 + lane]) : 0;
    int s0 = v0, s1 = v1, s2 = v2;
    for (int o = 1; o < 64; o <<= 1) {
      int n0 = __shfl_up(s0, o), n1 = __shfl_up(s1, o), n2 = __shfl_up(s2, o);
      if (lane >= o) { s0 += n0; s1 += n1; s2 += n2; }
    }
    int t0 = __shfl(s0, 63), t1 = __shfl(s1, 63), t2 = __shfl(s2, 63);
    if (lane < NW)       s_zp[lane]       = s0 - v0;
    if (64 + lane < NW)  s_zp[64 + lane]  = t0 + s1 - v1;
    if (128 + lane < NW) s_zp[128 + lane] = t0 + t1 + s2 - v2;
    if (lane == 0) s_nz = t0 + t1 + t2;
  }
  __syncthreads();
  // scatter nonzero into bucket-grouped order
  for (int p = tid; p < P; p += 1024) {
    unsigned bits = s_bits[p];
    if (bits != 0u) {
      unsigned slot = atomicAdd(&s_hist[bits >> 17], 1u);
      s_grp[slot] = (unsigned short)p;
    }
  }
  __syncthreads();
  int npos = num_pos[b];
  int nneg = min(3 * npos, P - 1);
  int nz = s_nz;
  float acc = 0.f;
  for (int j = tid; j < nneg; j += 1024) {
    unsigned bj = s_bits[j];
    int rk;
    if (bj == 0u) {
      int w = j >> 6;
      unsigned long long below = (j & 63) ? (s_zw[w] & ((1ull << (j & 63)) - 1ull)) : 0ull;
      rk = s_zp[w] + __popcll(below);
    } else {
      unsigned bu = bj >> 17;
      unsigned start = bu ? s_hist[bu - 1] : 0u;   // after scatter: hist[x] = end of x
      unsigned end = s_hist[bu];
      unsigned cnt = 0;
#pragma unroll 4
      for (unsigned t = start; t < end; ++t) {
        int k = s_grp[t];
        unsigned bk = s_bits[k];
        cnt += (bk < bj) || (bk == bj && k < j);
      }
      rk = nz + (int)(start + cnt);                // stable ascending rank of j
    }
    acc += __uint_as_float(s_bits[rk]);            // = ce[rk] if neg, 0 if pos
  }
  for (int o=32;o;o>>=1) acc += __shfl_xor(acc,o);
  if (lane==0) s_facc[wv]=acc;
  __syncthreads();
  if (tid==0){ float f=0; for(int i=0;i<16;i++) f+=s_facc[i]; atomicAdd(&accum[2], f); }
}

__global__ void k_final(const int* __restrict__ num_pos, const float* __restrict__ accum,
                        float* __restrict__ out, int B)
{
  int s = 0;
  for (int i = threadIdx.x; i < B; i += 64) s += num_pos[i];
  for (int o=32;o;o>>=1) s += __shfl_xor(s,o);
  if (threadIdx.x == 0) {
    float N = (float)s;
    out[0] = accum[0] / N;
    out[1] = (accum[1] + accum[2]) / N;
  }
}

extern "C" void kernel_launch(void* const* d_in, const int* in_sizes, int n_in,
                              void* d_out, int out_size, void* d_ws, size_t ws_size,
                              hipStream_t stream)
{
  const float* pred_conf = (const float*)d_in[0];
  const float* pred_loc  = (const float*)d_in[1];
  const float* priors    = (const float*)d_in[2];
  const float* truth     = (const float*)d_in[3];
  int  P  = in_sizes[2] / 4;
  long BP = in_sizes[1] / 4;          // B*P
  int  B  = (int)(BP / P);
  int  C  = (int)(in_sizes[0] / BP);
  int  G  = in_sizes[3] / (B * 5);

  char* ws = (char*)d_ws;
  size_t off = 0;
  int*   conf_t  = (int*)(ws + off);   off += sizeof(int)   * (size_t)BP;
  float* ce      = (float*)(ws + off); off += sizeof(float) * (size_t)BP;
  int*   over    = (int*)(ws + off);   off += sizeof(int)   * (size_t)BP;
  int*   num_pos = (int*)(ws + off);   off += sizeof(int)   * (size_t)B;
  float* accum   = (float*)(ws + off); off += 4 * sizeof(float);

  k_init     <<<1024, 256, 0, stream>>>(over, num_pos, accum, BP, B);
  k_bestprior<<<B * 8, 256, 0, stream>>>(priors, truth, over, B, P, G);
  k_match    <<<B * 8, 256, 0, stream>>>(pred_loc, priors, truth, over,
                                         conf_t, num_pos, accum, B, P, G);
  k_ce       <<<4096, 256, 0, stream>>>(pred_conf, conf_t, ce, accum, BP, C);
  k_negsel   <<<B, 1024, 0, stream>>>(ce, conf_t, num_pos, accum, P);
  k_final    <<<1, 64, 0, stream>>>(num_pos, accum, (float*)d_out, B);
}

// Round 5
// 203.931 us; speedup vs baseline: 2.1932x; 1.2376x over previous
//
#include <hip/hip_runtime.h>
#include <math.h>

#define MAXP 8732
#define MAXG 64
#define NBINS 16384   // float_bits >> 17 (sign+exp+6 mantissa bits)
#define NZW   ((MAXP + 63) / 64)

// IoU with the exact op order of the numpy reference; contraction off so the
// decision-critical values (argmax ties, <0.5 threshold) match numpy bit-for-bit.
__device__ __forceinline__ float iou_one(float px1,float py1,float px2,float py2,float area_p,
                                         float gx1,float gy1,float gx2,float gy2,float area_g){
#pragma clang fp contract(off)
  float ix = fminf(px2,gx2) - fmaxf(px1,gx1); ix = fmaxf(ix,0.0f);
  float iy = fminf(py2,gy2) - fmaxf(py1,gy1); iy = fmaxf(iy,0.0f);
  float inter = ix*iy;
  return inter / (area_p + area_g - inter);
}

// K0: workspace init (replaces hipMemsetAsync — the runtime fill kernel cost
// ~102 us/launch under graph capture). over=-1, num_pos=0, accum=0.
__global__ __launch_bounds__(256) void k_init(
    int* __restrict__ over, int* __restrict__ num_pos, float* __restrict__ accum,
    long n_over, int B)
{
  long i = (long)blockIdx.x * 256 + threadIdx.x;
  long stride = (long)gridDim.x * 256;
  for (long p = i; p < n_over; p += stride) over[p] = -1;
  if (blockIdx.x == 0) {
    for (int j = threadIdx.x; j < B; j += 256) num_pos[j] = 0;
    if (threadIdx.x < 4) accum[threadIdx.x] = 0.f;
  }
}

// K1a: one block per (b,g): best prior for gt g = first argmax over all P.
// 256 threads stride the prior list (~34 IoUs each), wave shuffle-reduce,
// LDS-reduce across 4 waves, single atomicMax into the override map
// over[b*P + p_best] = max g (last-wins == max-wins).
__global__ __launch_bounds__(256) void k_bestprior(
    const float* __restrict__ priors, const float* __restrict__ truth,
    int* __restrict__ over, int B, int P, int G)
{
#pragma clang fp contract(off)
  int b = blockIdx.x / G, g = blockIdx.x % G;
  int tid = threadIdx.x;
  int lane = tid & 63, wv = tid >> 6;
  __shared__ unsigned long long s_best[4];

  const float* t = truth + ((long)b*G + g)*5;
  float gx1=t[0], gy1=t[1], gx2=t[2], gy2=t[3];
  float ag = (gx2-gx1)*(gy2-gy1);
  unsigned long long best = 0ull;
  for (int p = tid; p < P; p += 256) {
    float4 pr = ((const float4*)priors)[p];
    float px1 = pr.x - 0.5f*pr.z, py1 = pr.y - 0.5f*pr.w;
    float px2 = pr.x + 0.5f*pr.z, py2 = pr.y + 0.5f*pr.w;
    float ap = (px2-px1)*(py2-py1);
    float v = iou_one(px1,py1,px2,py2,ap, gx1,gy1,gx2,gy2,ag);
    unsigned long long key = ((unsigned long long)__float_as_uint(v)<<32) | (unsigned)(P-1-p);
    if (key > best) best = key;
  }
  for (int o=32;o;o>>=1){
    unsigned lo = __shfl_xor((unsigned)best, o);
    unsigned hi = __shfl_xor((unsigned)(best>>32), o);
    unsigned long long other = ((unsigned long long)hi<<32)|lo;
    if (other > best) best = other;
  }
  if (lane == 0) s_best[wv] = best;
  __syncthreads();
  if (tid == 0) {
    unsigned long long m = s_best[0];
    if (s_best[1] > m) m = s_best[1];
    if (s_best[2] > m) m = s_best[2];
    if (s_best[3] > m) m = s_best[3];
    int pbest = P - 1 - (int)(unsigned)(m & 0xffffffffu);
    atomicMax(&over[(long)b*P + pbest], g);
  }
}

// K1b: per-prior best gt (first-max), forced overrides (from over[]),
// conf_t, and fused smooth-L1 (positives only).
__global__ __launch_bounds__(256) void k_match(
    const float* __restrict__ pred_loc, const float* __restrict__ priors,
    const float* __restrict__ truth, const int* __restrict__ over,
    int* __restrict__ conf_t, int* __restrict__ num_pos, float* __restrict__ accum,
    int B, int P, int G)
{
#pragma clang fp contract(off)
  const int SUB = 8;
  int b = blockIdx.x / SUB, sub = blockIdx.x % SUB;
  int tid = threadIdx.x;
  __shared__ float s_tb[MAXG*5];
  __shared__ float s_ag[MAXG];
  __shared__ float s_rf[4];
  __shared__ int   s_ri[4];
  for (int i = tid; i < G*5; i += 256) s_tb[i] = truth[(long)b*G*5 + i];
  __syncthreads();
  if (tid < G) {
    float x1=s_tb[tid*5], y1=s_tb[tid*5+1], x2=s_tb[tid*5+2], y2=s_tb[tid*5+3];
    s_ag[tid] = (x2-x1)*(y2-y1);
  }
  __syncthreads();
  int chunk = (P + SUB - 1)/SUB;
  int p0 = sub*chunk, p1 = min(p0+chunk, P);
  float lacc = 0.f; int pcnt = 0;
  for (int p = p0 + tid; p < p1; p += 256) {
    float4 pr = ((const float4*)priors)[p];
    float px1 = pr.x - 0.5f*pr.z, py1 = pr.y - 0.5f*pr.w;
    float px2 = pr.x + 0.5f*pr.z, py2 = pr.y + 0.5f*pr.w;
    float ap = (px2-px1)*(py2-py1);
    float bv = -1.0f; int bg = 0;
    for (int g = 0; g < G; ++g) {
      float v = iou_one(px1,py1,px2,py2,ap,
                        s_tb[g*5],s_tb[g*5+1],s_tb[g*5+2],s_tb[g*5+3], s_ag[g]);
      if (v > bv) { bv = v; bg = g; }       // first-max = np.argmax semantics
    }
    float ov = bv; int gi = bg;
    int ovg = over[(long)b*P + p];
    if (ovg >= 0) { ov = 2.0f; gi = ovg; }  // forced match (max g == last wins)
    float lb = s_tb[gi*5+4];
    int conf = (ov < 0.5f) ? 0 : (int)(lb + 1.0f);
    conf_t[(long)b*P + p] = conf;
    if (conf > 0) {
      pcnt++;
      float mx1=s_tb[gi*5], my1=s_tb[gi*5+1], mx2=s_tb[gi*5+2], my2=s_tb[gi*5+3];
      float l0 = ((mx1+mx2)*0.5f - pr.x)/pr.z;
      float l1 = ((my1+my2)*0.5f - pr.y)/pr.w;
      float l2 = __logf((mx2-mx1)/pr.z);
      float l3 = __logf((my2-my1)/pr.w);
      float4 pv = *((const float4*)(pred_loc + ((long)b*P + p)*4));
      float d, s = 0.f;
      d = fabsf(pv.x - l0); s += d < 1.f ? 0.5f*d*d : d - 0.5f;
      d = fabsf(pv.y - l1); s += d < 1.f ? 0.5f*d*d : d - 0.5f;
      d = fabsf(pv.z - l2); s += d < 1.f ? 0.5f*d*d : d - 0.5f;
      d = fabsf(pv.w - l3); s += d < 1.f ? 0.5f*d*d : d - 0.5f;
      lacc += s;
    }
  }
  int lane = tid & 63, wv = tid >> 6;
  for (int o=32;o;o>>=1){ lacc += __shfl_xor(lacc,o); pcnt += __shfl_xor(pcnt,o); }
  if (lane==0){ s_rf[wv]=lacc; s_ri[wv]=pcnt; }
  __syncthreads();
  if (tid==0){
    atomicAdd(&accum[0], s_rf[0]+s_rf[1]+s_rf[2]+s_rf[3]);
    atomicAdd(&num_pos[b], s_ri[0]+s_ri[1]+s_ri[2]+s_ri[3]);
  }
}

// K2: 16 lanes per row, 4 rows per wave per iteration. Each lane holds 6
// elements; 4-step quarter-wave shuffles amortized across 4 rows.
__global__ __launch_bounds__(256) void k_ce(
  const float* __restrict__ pred_conf, const int* __restrict__ conf_t,
  float* __restrict__ ce, float* __restrict__ accum, long rows, int C)
{
  const int tid = threadIdx.x;
  const int lane = tid & 63;
  const int wv = tid >> 6;
  const int g = lane >> 4;        // row group 0..3 within wave
  const int l = lane & 15;        // lane within group
  long wave = (long)blockIdx.x * 4 + wv;
  long nw = (long)gridDim.x * 4;
  float pacc = 0.f;
  for (long r0 = wave * 4; r0 < rows; r0 += nw * 4) {
    long row = r0 + g;
    bool valid = row < rows;
    const float* cp = pred_conf + (valid ? row : 0) * (long)C;
    float x0 = cp[l];
    float x1 = cp[l + 16];
    float x2 = cp[l + 32];
    float x3 = cp[l + 48];
    float x4 = cp[l + 64];
    float x5 = (l == 0) ? cp[80] : -INFINITY;
    float m = fmaxf(fmaxf(fmaxf(x0,x1),fmaxf(x2,x3)),fmaxf(x4,x5));
    for (int o = 8; o; o >>= 1) m = fmaxf(m, __shfl_xor(m, o));
    float s = __expf(x0-m)+__expf(x1-m)+__expf(x2-m)
            + __expf(x3-m)+__expf(x4-m)+__expf(x5-m);   // exp(-inf)=0
    int ct = valid ? conf_t[row] : 0;
    float tv = (ct == l      ? x0 : 0.f)
             + (ct == l+16   ? x1 : 0.f)
             + (ct == l+32   ? x2 : 0.f)
             + (ct == l+48   ? x3 : 0.f)
             + (ct == l+64   ? x4 : 0.f)
             + ((ct == 80 && l == 0) ? x5 : 0.f);
    for (int o = 8; o; o >>= 1) { s += __shfl_xor(s, o); tv += __shfl_xor(tv, o); }
    float cev = __logf(s) + m - tv;
    if (valid && l == 0) { ce[row] = cev; if (ct > 0) pacc += cev; }
  }
  for (int o = 32; o; o >>= 1) pacc += __shfl_xor(pacc, o);
  __shared__ float s_f[4];
  if (lane == 0) s_f[wv] = pacc;
  __syncthreads();
  if (threadIdx.x == 0) atomicAdd(&accum[1], s_f[0]+s_f[1]+s_f[2]+s_f[3]);
}

// K3: quirky negative mask. neg contribution = sum over j<num_neg of
// loss_mine[rank(j)] where rank(j) = stable ascending rank of loss_mine[j].
// Zero-class handled analytically via ballot-prefix; nonzero via 16384-bin
// counting sort with within-bucket stable-rank scan.
__global__ __launch_bounds__(1024) void k_negsel(
    const float* __restrict__ ce, const int* __restrict__ conf_t,
    const int* __restrict__ num_pos, float* __restrict__ accum, int P)
{
  const int b = blockIdx.x;
  const int tid = threadIdx.x;
  const int lane = tid & 63, wv = tid >> 6;
  __shared__ unsigned s_bits[MAXP];
  __shared__ unsigned s_hist[NBINS];
  __shared__ unsigned short s_grp[MAXP];
  __shared__ unsigned long long s_zw[NZW];
  __shared__ int s_zp[NZW];
  __shared__ unsigned s_wsum[16];
  __shared__ float s_facc[16];
  __shared__ int s_nz;

  const int NW = (P + 63) >> 6;
  long base = (long)b * P;
  for (int p = tid; p < P; p += 1024) {
    int ct = conf_t[base + p];
    float v = ce[base + p];
    s_bits[p] = (ct > 0) ? 0u : __float_as_uint(v);   // loss_mine bits (>=0, monotone)
  }
  for (int i = tid; i < NBINS; i += 1024) s_hist[i] = 0;
  __syncthreads();
  // zero-mask words (ballot) + nonzero histogram
  int Pr = (P + 1023) & ~1023;
  for (int p = tid; p < Pr; p += 1024) {
    unsigned bits = (p < P) ? s_bits[p] : 1u;   // out-of-range: "nonzero", no hist
    unsigned long long mask = __ballot(bits == 0u);
    int w = p >> 6;
    if (lane == 0 && w < NW) s_zw[w] = mask;
    if (p < P && bits != 0u) atomicAdd(&s_hist[bits >> 17], 1u);
  }
  __syncthreads();
  // exclusive scan over NBINS (16 bins/thread)
  unsigned loc[16]; unsigned tot = 0;
  int hbase = tid * 16;
#pragma unroll
  for (int i = 0; i < 16; ++i) { loc[i] = s_hist[hbase + i]; tot += loc[i]; }
  unsigned incl = tot;
  for (int o = 1; o < 64; o <<= 1) {
    unsigned n = __shfl_up(incl, o);
    if (lane >= o) incl += n;
  }
  if (lane == 63) s_wsum[wv] = incl;
  __syncthreads();
  if (tid == 0) {
    unsigned r = 0;
    for (int i = 0; i < 16; ++i) { unsigned t = s_wsum[i]; s_wsum[i] = r; r += t; }
  }
  __syncthreads();
  unsigned run = incl - tot + s_wsum[wv];
#pragma unroll
  for (int i = 0; i < 16; ++i) { s_hist[hbase + i] = run; run += loc[i]; }
  // wave 0: zero-class prefix over NW (<=192) mask words
  if (wv == 0) {
    int v0 = (lane < NW)       ? __popcll(s_zw[lane])       : 0;
    int v1 = (64 + lane < NW)  ? __popcll(s_zw[64 + lane])  : 0;
    int v2 = (128 + lane < NW) ? __popcll(s_zw[128 + lane]) : 0;
    int s0 = v0, s1 = v1, s2 = v2;
    for (int o = 1; o < 64; o <<= 1) {
      int n0 = __shfl_up(s0, o), n1 = __shfl_up(s1, o), n2 = __shfl_up(s2, o);
      if (lane >= o) { s0 += n0; s1 += n1; s2 += n2; }
    }
    int t0 = __shfl(s0, 63), t1 = __shfl(s1, 63), t2 = __shfl(s2, 63);
    if (lane < NW)       s_zp[lane]       = s0 - v0;
    if (64 + lane < NW)  s_zp[64 + lane]  = t0 + s1 - v1;
    if (128 + lane < NW) s_zp[128 + lane] = t0 + t1 + s2 - v2;
    if (lane == 0) s_nz = t0 + t1 + t2;
  }
  __syncthreads();
  // scatter nonzero into bucket-grouped order
  for (int p = tid; p < P; p += 1024) {
    unsigned bits = s_bits[p];
    if (bits != 0u) {
      unsigned slot = atomicAdd(&s_hist[bits >> 17], 1u);
      s_grp[slot] = (unsigned short)p;
    }
  }
  __syncthreads();
  int npos = num_pos[b];
  int nneg = min(3 * npos, P - 1);
  int nz = s_nz;
  float acc = 0.f;
  for (int j = tid; j < nneg; j += 1024) {
    unsigned bj = s_bits[j];
    int rk;
    if (bj == 0u) {
      int w = j >> 6;
      unsigned long long below = (j & 63) ? (s_zw[w] & ((1ull << (j & 63)) - 1ull)) : 0ull;
      rk = s_zp[w] + __popcll(below);
    } else {
      unsigned bu = bj >> 17;
      unsigned start = bu ? s_hist[bu - 1] : 0u;   // after scatter: hist[x] = end of x
      unsigned end = s_hist[bu];
      unsigned cnt = 0;
#pragma unroll 4
      for (unsigned t = start; t < end; ++t) {
        int k = s_grp[t];
        unsigned bk = s_bits[k];
        cnt += (bk < bj) || (bk == bj && k < j);
      }
      rk = nz + (int)(start + cnt);                // stable ascending rank of j
    }
    acc += __uint_as_float(s_bits[rk]);            // = ce[rk] if neg, 0 if pos
  }
  for (int o=32;o;o>>=1) acc += __shfl_xor(acc,o);
  if (lane==0) s_facc[wv]=acc;
  __syncthreads();
  if (tid==0){ float f=0; for(int i=0;i<16;i++) f+=s_facc[i]; atomicAdd(&accum[2], f); }
}

__global__ void k_final(const int* __restrict__ num_pos, const float* __restrict__ accum,
                        float* __restrict__ out, int B)
{
  int s = 0;
  for (int i = threadIdx.x; i < B; i += 64) s += num_pos[i];
  for (int o=32;o;o>>=1) s += __shfl_xor(s,o);
  if (threadIdx.x == 0) {
    float N = (float)s;
    out[0] = accum[0] / N;
    out[1] = (accum[1] + accum[2]) / N;
  }
}

extern "C" void kernel_launch(void* const* d_in, const int* in_sizes, int n_in,
                              void* d_out, int out_size, void* d_ws, size_t ws_size,
                              hipStream_t stream)
{
  const float* pred_conf = (const float*)d_in[0];
  const float* pred_loc  = (const float*)d_in[1];
  const float* priors    = (const float*)d_in[2];
  const float* truth     = (const float*)d_in[3];
  int  P  = in_sizes[2] / 4;
  long BP = in_sizes[1] / 4;          // B*P
  int  B  = (int)(BP / P);
  int  C  = (int)(in_sizes[0] / BP);
  int  G  = in_sizes[3] / (B * 5);

  char* ws = (char*)d_ws;
  size_t off = 0;
  int*   conf_t  = (int*)(ws + off);   off += sizeof(int)   * (size_t)BP;
  float* ce      = (float*)(ws + off); off += sizeof(float) * (size_t)BP;
  int*   over    = (int*)(ws + off);   off += sizeof(int)   * (size_t)BP;
  int*   num_pos = (int*)(ws + off);   off += sizeof(int)   * (size_t)B;
  float* accum   = (float*)(ws + off); off += 4 * sizeof(float);

  k_init     <<<1024, 256, 0, stream>>>(over, num_pos, accum, BP, B);
  k_bestprior<<<B * G, 256, 0, stream>>>(priors, truth, over, B, P, G);
  k_match    <<<B * 8, 256, 0, stream>>>(pred_loc, priors, truth, over,
                                         conf_t, num_pos, accum, B, P, G);
  k_ce       <<<4096, 256, 0, stream>>>(pred_conf, conf_t, ce, accum, BP, C);
  k_negsel   <<<B, 1024, 0, stream>>>(ce, conf_t, num_pos, accum, P);
  k_final    <<<1, 64, 0, stream>>>(num_pos, accum, (float*)d_out, B);
}